// Round 1
// baseline (2328.649 us; speedup 1.0000x reference)
//
#include <hip/hip_runtime.h>
#include <hip/hip_bf16.h>

#define WAVE 64

__device__ __forceinline__ float rdlane(float v, int l) {
    return __uint_as_float(__builtin_amdgcn_readlane(__float_as_uint(v), l));
}

// ---------------- init: zero accumulators, deg_sl starts at 1 (self-loop) ---
__global__ void k_init(float* __restrict__ nef6, float* __restrict__ deg,
                       float* __restrict__ degsl, double* __restrict__ sums, int n) {
    int i = blockIdx.x * blockDim.x + threadIdx.x;
    if (i < 128) sums[i] = 0.0;
    if (i < n) {
        deg[i] = 0.f;
        degsl[i] = 1.f;
#pragma unroll
        for (int c = 0; c < 6; ++c) nef6[i * 6 + c] = 0.f;
    }
}

// ---------------- edge-MLP injection: only first 6 output cols are used -----
__global__ __launch_bounds__(256) void k_edge_inject(
    const int* __restrict__ ei, const float* __restrict__ ea,
    const float* __restrict__ We1, const float* __restrict__ be1,
    const float* __restrict__ We2, const float* __restrict__ be2,
    float* __restrict__ nef6, float* __restrict__ deg, float* __restrict__ degsl,
    int E) {
    __shared__ float sWe1[128], sbe1[64], sWe2[64 * 6], sbe2[6];
    int t = threadIdx.x;
    if (t < 128) sWe1[t] = We1[t];
    if (t < 64) {
        sbe1[t] = be1[t];
#pragma unroll
        for (int c = 0; c < 6; ++c) sWe2[t * 6 + c] = We2[t * 64 + c];
    }
    if (t < 6) sbe2[t] = be2[t];
    __syncthreads();

    int e = blockIdx.x * blockDim.x + t;
    if (e >= E) return;
    float a0 = ea[2 * e], a1 = ea[2 * e + 1];
    float acc[6];
#pragma unroll
    for (int c = 0; c < 6; ++c) acc[c] = sbe2[c];
#pragma unroll
    for (int j = 0; j < 64; ++j) {
        float h = fmaf(a0, sWe1[j], fmaf(a1, sWe1[64 + j], sbe1[j]));
        h = fmaxf(h, 0.f);
#pragma unroll
        for (int c = 0; c < 6; ++c) acc[c] = fmaf(h, sWe2[j * 6 + c], acc[c]);
    }
    int s = ei[e], d = ei[E + e];
#pragma unroll
    for (int c = 0; c < 6; ++c) {
        unsafeAtomicAdd(&nef6[(size_t)s * 6 + c], acc[c]);
        unsafeAtomicAdd(&nef6[(size_t)d * 6 + c], acc[c]);
    }
    unsafeAtomicAdd(&deg[s], 1.f);
    unsafeAtomicAdd(&deg[d], 1.f);
    unsafeAtomicAdd(&degsl[d], 1.f);  // GCN in-degree (+1 self-loop in init)
}

// ---------------- x' = x + 0.5*nef/deg ; dinv = deg_sl^-0.5 -----------------
__global__ void k_finalize_x(const float* __restrict__ x, const float* __restrict__ nef6,
                             const float* __restrict__ deg, const float* __restrict__ degsl,
                             float* __restrict__ xp, float* __restrict__ dinv, int n) {
    int i = blockIdx.x * blockDim.x + threadIdx.x;
    if (i >= n) return;
    float inv = 0.5f / fmaxf(deg[i], 1.f);
#pragma unroll
    for (int c = 0; c < 6; ++c) xp[i * 6 + c] = x[i * 6 + c] + nef6[i * 6 + c] * inv;
    dinv[i] = 1.f / sqrtf(degsl[i]);
}

// ---------------- layer 1: hW = x'(N,6) @ W1(6,64); agg = hW*dinv^2 ---------
__global__ __launch_bounds__(256) void k_mm1(const float* __restrict__ xp,
                                             const float* __restrict__ W1,
                                             const float* __restrict__ dinv,
                                             float* __restrict__ hW, float* __restrict__ agg,
                                             int n) {
    int lane = threadIdx.x & 63;
    int wid = (blockIdx.x * blockDim.x + threadIdx.x) >> 6;
    int nw = (gridDim.x * blockDim.x) >> 6;
    float w[6];
#pragma unroll
    for (int c = 0; c < 6; ++c) w[c] = W1[c * 64 + lane];
    for (int i = wid; i < n; i += nw) {
        float xv = (lane < 6) ? xp[(size_t)i * 6 + lane] : 0.f;
        float acc = 0.f;
#pragma unroll
        for (int c = 0; c < 6; ++c) acc = fmaf(rdlane(xv, c), w[c], acc);
        float dv = dinv[i];
        hW[(size_t)i * 64 + lane] = acc;
        agg[(size_t)i * 64 + lane] = acc * dv * dv;
    }
}

// ------- layers 2/3: in = relu(agg_prev + b_prev); hW = in@W; agg = hW*dinv^2
__global__ __launch_bounds__(256) void k_mm(const float* __restrict__ aggin,
                                            const float* __restrict__ bias,
                                            const float* __restrict__ W,
                                            const float* __restrict__ dinv,
                                            float* __restrict__ hW, float* __restrict__ aggout,
                                            int n) {
    int lane = threadIdx.x & 63;
    int wid = (blockIdx.x * blockDim.x + threadIdx.x) >> 6;
    int nw = (gridDim.x * blockDim.x) >> 6;
    float w[64];
#pragma unroll
    for (int c = 0; c < 64; ++c) w[c] = W[c * 64 + lane];
    float b = bias[lane];
    for (int i = wid; i < n; i += nw) {
        float hv = fmaxf(aggin[(size_t)i * 64 + lane] + b, 0.f);
        float acc = 0.f;
#pragma unroll
        for (int c = 0; c < 64; ++c) acc = fmaf(rdlane(hv, c), w[c], acc);
        float dv = dinv[i];
        hW[(size_t)i * 64 + lane] = acc;
        aggout[(size_t)i * 64 + lane] = acc * dv * dv;
    }
}

// ---------------- edge aggregation: wave per edge, lane = feature -----------
__global__ __launch_bounds__(256) void k_edge_agg(const int* __restrict__ ei,
                                                  const float* __restrict__ dinv,
                                                  const float* __restrict__ hW,
                                                  float* __restrict__ agg, int E) {
    size_t t = (size_t)blockIdx.x * blockDim.x + threadIdx.x;
    int e = (int)(t >> 6);
    int lane = (int)(t & 63);
    if (e >= E) return;
    int s = ei[e], d = ei[E + e];
    float w = dinv[s] * dinv[d];
    float v = hW[(size_t)s * 64 + lane] * w;
    unsafeAtomicAdd(&agg[(size_t)d * 64 + lane], v);
}

// ---------------- pooled sum / sumsq in double ------------------------------
__global__ void k_reduce(const float* __restrict__ agg, const float* __restrict__ b3,
                         double* __restrict__ sums, int n) {
    int t = blockIdx.x * blockDim.x + threadIdx.x;
    int lane = t & 63;
    int r0 = t >> 6;
    int stride = (gridDim.x * blockDim.x) >> 6;
    float b = b3[lane];
    double s = 0.0, s2 = 0.0;
    for (int i = r0; i < n; i += stride) {
        float v = agg[(size_t)i * 64 + lane] + b;
        s += v;
        s2 += (double)v * (double)v;
    }
    unsafeAtomicAdd(&sums[lane], s);
    unsafeAtomicAdd(&sums[64 + lane], s2);
}

// ---------------- head MLP + sigmoid (single wave) --------------------------
__global__ void k_head(const double* __restrict__ sums,
                       const float* __restrict__ Wp1, const float* __restrict__ bp1,
                       const float* __restrict__ Wp2, const float* __restrict__ bp2,
                       const float* __restrict__ Wp3, const float* __restrict__ bp3,
                       float* __restrict__ out, int n) {
    __shared__ float comb[192], p1[64], p2[32];
    int t = threadIdx.x;
    if (t < 64) {
        double s = sums[t], s2 = sums[64 + t];
        double m = s / n;
        double var = (s2 - s * s / n) / (double)(n - 1);
        float mf = (float)m;
        float sd = (float)sqrt(var > 0.0 ? var : 0.0);
        comb[t] = mf;
        comb[64 + t] = mf;
        comb[128 + t] = sd;
    }
    __syncthreads();
    if (t < 64) {
        float acc = bp1[t];
        for (int k = 0; k < 192; ++k) acc = fmaf(comb[k], Wp1[k * 64 + t], acc);
        p1[t] = fmaxf(acc, 0.f);
    }
    __syncthreads();
    if (t < 32) {
        float acc = bp2[t];
        for (int k = 0; k < 64; ++k) acc = fmaf(p1[k], Wp2[k * 32 + t], acc);
        p2[t] = fmaxf(acc, 0.f);
    }
    __syncthreads();
    if (t == 0) {
        float acc = bp3[0];
        for (int k = 0; k < 32; ++k) acc = fmaf(p2[k], Wp3[k], acc);
        out[0] = 1.f / (1.f + expf(-acc));
    }
}

extern "C" void kernel_launch(void* const* d_in, const int* in_sizes, int n_in,
                              void* d_out, int out_size, void* d_ws, size_t ws_size,
                              hipStream_t stream) {
    const float* x   = (const float*)d_in[0];
    const int*   ei  = (const int*)d_in[1];
    const float* ea  = (const float*)d_in[2];
    const float* W1  = (const float*)d_in[3];
    const float* b1  = (const float*)d_in[4];
    const float* W2  = (const float*)d_in[5];
    const float* b2  = (const float*)d_in[6];
    const float* W3  = (const float*)d_in[7];
    const float* b3  = (const float*)d_in[8];
    const float* We1 = (const float*)d_in[9];
    const float* be1 = (const float*)d_in[10];
    const float* We2 = (const float*)d_in[11];
    const float* be2 = (const float*)d_in[12];
    const float* Wp1 = (const float*)d_in[13];
    const float* bp1 = (const float*)d_in[14];
    const float* Wp2 = (const float*)d_in[15];
    const float* bp2 = (const float*)d_in[16];
    const float* Wp3 = (const float*)d_in[17];
    const float* bp3 = (const float*)d_in[18];

    const int N = in_sizes[0] / 6;
    const int E = in_sizes[1] / 2;

    // workspace layout: 128 doubles, then float arrays
    double* sums = (double*)d_ws;
    float* fbase = (float*)((char*)d_ws + 1024);
    float* nef6  = fbase;                 fbase += (size_t)N * 6;
    float* deg   = fbase;                 fbase += N;
    float* degsl = fbase;                 fbase += N;
    float* dinv  = fbase;                 fbase += N;
    float* xp    = fbase;                 fbase += (size_t)N * 6;
    float* bufA  = fbase;                 fbase += (size_t)N * 64;
    float* bufB  = fbase;                 fbase += (size_t)N * 64;
    float* bufC  = fbase;                 fbase += (size_t)N * 64;

    const int TB = 256;
    dim3 blk(TB);

    k_init<<<dim3((N + TB - 1) / TB), blk, 0, stream>>>(nef6, deg, degsl, sums, N);
    k_edge_inject<<<dim3((E + TB - 1) / TB), blk, 0, stream>>>(ei, ea, We1, be1, We2, be2,
                                                               nef6, deg, degsl, E);
    k_finalize_x<<<dim3((N + TB - 1) / TB), blk, 0, stream>>>(x, nef6, deg, degsl, xp, dinv, N);

    // layer 1
    k_mm1<<<dim3(1024), blk, 0, stream>>>(xp, W1, dinv, bufB, bufC, N);
    k_edge_agg<<<dim3((unsigned)(((size_t)E * 64 + TB - 1) / TB)), blk, 0, stream>>>(ei, dinv, bufB, bufC, E);
    // layer 2 (applies b1+relu to layer-1 agg)
    k_mm<<<dim3(1024), blk, 0, stream>>>(bufC, b1, W2, dinv, bufB, bufA, N);
    k_edge_agg<<<dim3((unsigned)(((size_t)E * 64 + TB - 1) / TB)), blk, 0, stream>>>(ei, dinv, bufB, bufA, E);
    // layer 3 (applies b2+relu to layer-2 agg)
    k_mm<<<dim3(1024), blk, 0, stream>>>(bufA, b2, W3, dinv, bufB, bufC, N);
    k_edge_agg<<<dim3((unsigned)(((size_t)E * 64 + TB - 1) / TB)), blk, 0, stream>>>(ei, dinv, bufB, bufC, E);

    // pooling (+b3, no relu) and head
    k_reduce<<<dim3(512), blk, 0, stream>>>(bufC, b3, sums, N);
    k_head<<<dim3(1), dim3(64), 0, stream>>>(sums, Wp1, bp1, Wp2, bp2, Wp3, bp3,
                                             (float*)d_out, N);
}

// Round 2
// 1519.717 us; speedup vs baseline: 1.5323x; 1.5323x over previous
//
#include <hip/hip_runtime.h>
#include <hip/hip_bf16.h>
#include <stdint.h>

__device__ __forceinline__ float rdlane(float v, int l) {
    return __uint_as_float(__builtin_amdgcn_readlane(__float_as_uint(v), l));
}

// ---------------- zero counters + pooled sums -------------------------------
__global__ void k_zero(int* __restrict__ cnt, double* __restrict__ sums, int n) {
    int i = blockIdx.x * blockDim.x + threadIdx.x;
    if (i < 128) sums[i] = 0.0;
    if (i < n) cnt[i] = 0;
}

// ---------------- incidence histogram: cnt[i] = #edges touching i -----------
__global__ __launch_bounds__(256) void k_hist(const int* __restrict__ ei,
                                              int* __restrict__ cnt, int E) {
    int e = blockIdx.x * blockDim.x + threadIdx.x;
    if (e >= E) return;
    atomicAdd(&cnt[ei[e]], 1);
    atomicAdd(&cnt[ei[E + e]], 1);
}

// ---------------- scan pass 1: per-block totals -----------------------------
__global__ __launch_bounds__(256) void k_scan1(const int* __restrict__ cnt,
                                               int* __restrict__ bsum, int n) {
    __shared__ int l[256];
    int i = blockIdx.x * 256 + threadIdx.x;
    l[threadIdx.x] = (i < n) ? cnt[i] : 0;
    __syncthreads();
    for (int s = 128; s > 0; s >>= 1) {
        if (threadIdx.x < s) l[threadIdx.x] += l[threadIdx.x + s];
        __syncthreads();
    }
    if (threadIdx.x == 0) bsum[blockIdx.x] = l[0];
}

// ---------------- scan pass 2: exclusive scan of block totals (nb<=512) -----
__global__ __launch_bounds__(512) void k_scan2(int* __restrict__ bsum, int nb,
                                               int* __restrict__ offN) {
    __shared__ int l[512];
    int t = threadIdx.x;
    int v = (t < nb) ? bsum[t] : 0;
    l[t] = v;
    __syncthreads();
    for (int s = 1; s < 512; s <<= 1) {
        int tmp = (t >= s) ? l[t - s] : 0;
        __syncthreads();
        l[t] += tmp;
        __syncthreads();
    }
    if (t < nb) bsum[t] = l[t] - v;  // exclusive
    if (t == 511) *offN = l[511];    // grand total = 2E
}

// ---------------- scan pass 3: off[i], cursor cur[i] ------------------------
__global__ __launch_bounds__(256) void k_scan3(const int* __restrict__ cnt,
                                               const int* __restrict__ bsum,
                                               int* __restrict__ off, int* __restrict__ cur,
                                               int n) {
    __shared__ int l[256];
    int i = blockIdx.x * 256 + threadIdx.x;
    int v = (i < n) ? cnt[i] : 0;
    l[threadIdx.x] = v;
    __syncthreads();
    for (int s = 1; s < 256; s <<= 1) {
        int tmp = (threadIdx.x >= (unsigned)s) ? l[threadIdx.x - s] : 0;
        __syncthreads();
        l[threadIdx.x] += tmp;
        __syncthreads();
    }
    if (i < n) {
        int excl = l[threadIdx.x] - v + bsum[blockIdx.x];
        off[i] = excl;
        cur[i] = excl;
    }
}

// ------- edge MLP (6 used cols only) + CSR scatter (2 int atomics/edge) -----
__global__ __launch_bounds__(256) void k_edge_mlp(
    const int* __restrict__ ei, const float* __restrict__ ea,
    const float* __restrict__ We1, const float* __restrict__ be1,
    const float* __restrict__ We2, const float* __restrict__ be2,
    float* __restrict__ ef6, int* __restrict__ cur, unsigned* __restrict__ adj,
    int E) {
    __shared__ float sWe1[128], sbe1[64], sWe2[64 * 6], sbe2[6];
    int t = threadIdx.x;
    if (t < 128) sWe1[t] = We1[t];
    if (t < 64) {
        sbe1[t] = be1[t];
#pragma unroll
        for (int c = 0; c < 6; ++c) sWe2[t * 6 + c] = We2[t * 64 + c];
    }
    if (t < 6) sbe2[t] = be2[t];
    __syncthreads();

    int e = blockIdx.x * blockDim.x + t;
    if (e >= E) return;
    float a0 = ea[2 * e], a1 = ea[2 * e + 1];
    float acc[6];
#pragma unroll
    for (int c = 0; c < 6; ++c) acc[c] = sbe2[c];
#pragma unroll
    for (int j = 0; j < 64; ++j) {
        float h = fmaf(a0, sWe1[j], fmaf(a1, sWe1[64 + j], sbe1[j]));
        h = fmaxf(h, 0.f);
#pragma unroll
        for (int c = 0; c < 6; ++c) acc[c] = fmaf(h, sWe2[j * 6 + c], acc[c]);
    }
    float2* p = (float2*)(ef6 + (size_t)e * 6);
    p[0] = make_float2(acc[0], acc[1]);
    p[1] = make_float2(acc[2], acc[3]);
    p[2] = make_float2(acc[4], acc[5]);

    int s = ei[e], d = ei[E + e];
    int p0 = atomicAdd(&cur[s], 1);
    adj[p0] = ((unsigned)e << 1);
    int p1 = atomicAdd(&cur[d], 1);
    adj[p1] = ((unsigned)e << 1) | 1u;
}

// ------- per node: nef gather -> x', deg, in-degree -> dinv -----------------
__global__ __launch_bounds__(256) void k_nef_x(
    const unsigned* __restrict__ adj, const int* __restrict__ off,
    const float* __restrict__ ef6, const float* __restrict__ x,
    float* __restrict__ xp, float* __restrict__ dinv, int n) {
    int i = blockIdx.x * blockDim.x + threadIdx.x;
    if (i >= n) return;
    int b = off[i], eend = off[i + 1];
    float a0 = 0.f, a1 = 0.f, a2 = 0.f, a3 = 0.f, a4 = 0.f, a5 = 0.f;
    int indeg = 0;
    for (int j = b; j < eend; ++j) {
        unsigned a = adj[j];
        indeg += (int)(a & 1u);
        const float2* p = (const float2*)(ef6 + (size_t)(a >> 1) * 6);
        float2 q0 = p[0], q1 = p[1], q2 = p[2];
        a0 += q0.x; a1 += q0.y; a2 += q1.x;
        a3 += q1.y; a4 += q2.x; a5 += q2.y;
    }
    float degf = (float)(eend - b);
    float inv = 0.5f / fmaxf(degf, 1.f);
    xp[(size_t)i * 6 + 0] = x[(size_t)i * 6 + 0] + a0 * inv;
    xp[(size_t)i * 6 + 1] = x[(size_t)i * 6 + 1] + a1 * inv;
    xp[(size_t)i * 6 + 2] = x[(size_t)i * 6 + 2] + a2 * inv;
    xp[(size_t)i * 6 + 3] = x[(size_t)i * 6 + 3] + a3 * inv;
    xp[(size_t)i * 6 + 4] = x[(size_t)i * 6 + 4] + a4 * inv;
    xp[(size_t)i * 6 + 5] = x[(size_t)i * 6 + 5] + a5 * inv;
    dinv[i] = 1.f / sqrtf(1.f + (float)indeg);
}

// ---------------- layer 1: hW = x'(N,6) @ W1(6,64) --------------------------
__global__ __launch_bounds__(256) void k_mm1(const float* __restrict__ xp,
                                             const float* __restrict__ W1,
                                             float* __restrict__ hW, int n) {
    int lane = threadIdx.x & 63;
    int wid = (blockIdx.x * blockDim.x + threadIdx.x) >> 6;
    int nw = (gridDim.x * blockDim.x) >> 6;
    float w[6];
#pragma unroll
    for (int c = 0; c < 6; ++c) w[c] = W1[c * 64 + lane];
    for (int i = wid; i < n; i += nw) {
        float xv = (lane < 6) ? xp[(size_t)i * 6 + lane] : 0.f;
        float acc = 0.f;
#pragma unroll
        for (int c = 0; c < 6; ++c) acc = fmaf(rdlane(xv, c), w[c], acc);
        hW[(size_t)i * 64 + lane] = acc;
    }
}

// ------- layers 2/3: in = relu(agg_prev + b_prev); hW = in @ W --------------
__global__ __launch_bounds__(256) void k_mm(const float* __restrict__ aggin,
                                            const float* __restrict__ bias,
                                            const float* __restrict__ W,
                                            float* __restrict__ hW, int n) {
    int lane = threadIdx.x & 63;
    int wid = (blockIdx.x * blockDim.x + threadIdx.x) >> 6;
    int nw = (gridDim.x * blockDim.x) >> 6;
    float w[64];
#pragma unroll
    for (int c = 0; c < 64; ++c) w[c] = W[c * 64 + lane];
    float b = bias[lane];
    for (int i = wid; i < n; i += nw) {
        float hv = fmaxf(aggin[(size_t)i * 64 + lane] + b, 0.f);
        float acc = 0.f;
#pragma unroll
        for (int c = 0; c < 64; ++c) acc = fmaf(rdlane(hv, c), w[c], acc);
        hW[(size_t)i * 64 + lane] = acc;
    }
}

// ------- GCN aggregation: wave per node, lane = feature, gather in-edges ----
__global__ __launch_bounds__(256) void k_gather(const int* __restrict__ ei,
                                                const unsigned* __restrict__ adj,
                                                const int* __restrict__ off,
                                                const float* __restrict__ dinv,
                                                const float* __restrict__ hW,
                                                float* __restrict__ agg, int n, int E) {
    int w = (int)(((size_t)blockIdx.x * blockDim.x + threadIdx.x) >> 6);
    int lane = threadIdx.x & 63;
    if (w >= n) return;
    float di = dinv[w];
    float acc = di * hW[(size_t)w * 64 + lane];  // self-loop (di^2 after final mul)
    int b = off[w], eend = off[w + 1];
    for (int j = b; j < eend; ++j) {
        unsigned a = adj[j];
        if (a & 1u) {  // this node is dst of edge e -> gather from src
            int s = ei[a >> 1];
            acc = fmaf(dinv[s], hW[(size_t)s * 64 + lane], acc);
        }
    }
    agg[(size_t)w * 64 + lane] = di * acc;
}

// ---------------- pooled sum / sumsq in double ------------------------------
__global__ void k_reduce(const float* __restrict__ agg, const float* __restrict__ b3,
                         double* __restrict__ sums, int n) {
    int t = blockIdx.x * blockDim.x + threadIdx.x;
    int lane = t & 63;
    int r0 = t >> 6;
    int stride = (gridDim.x * blockDim.x) >> 6;
    float b = b3[lane];
    double s = 0.0, s2 = 0.0;
    for (int i = r0; i < n; i += stride) {
        float v = agg[(size_t)i * 64 + lane] + b;
        s += v;
        s2 += (double)v * (double)v;
    }
    unsafeAtomicAdd(&sums[lane], s);
    unsafeAtomicAdd(&sums[64 + lane], s2);
}

// ---------------- head MLP + sigmoid (single block) -------------------------
__global__ void k_head(const double* __restrict__ sums,
                       const float* __restrict__ Wp1, const float* __restrict__ bp1,
                       const float* __restrict__ Wp2, const float* __restrict__ bp2,
                       const float* __restrict__ Wp3, const float* __restrict__ bp3,
                       float* __restrict__ out, int n) {
    __shared__ float comb[192], p1[64], p2[32];
    int t = threadIdx.x;
    if (t < 64) {
        double s = sums[t], s2 = sums[64 + t];
        double m = s / n;
        double var = (s2 - s * s / n) / (double)(n - 1);
        float mf = (float)m;
        float sd = (float)sqrt(var > 0.0 ? var : 0.0);
        comb[t] = mf;
        comb[64 + t] = mf;
        comb[128 + t] = sd;
    }
    __syncthreads();
    if (t < 64) {
        float acc = bp1[t];
        for (int k = 0; k < 192; ++k) acc = fmaf(comb[k], Wp1[k * 64 + t], acc);
        p1[t] = fmaxf(acc, 0.f);
    }
    __syncthreads();
    if (t < 32) {
        float acc = bp2[t];
        for (int k = 0; k < 64; ++k) acc = fmaf(p1[k], Wp2[k * 32 + t], acc);
        p2[t] = fmaxf(acc, 0.f);
    }
    __syncthreads();
    if (t == 0) {
        float acc = bp3[0];
        for (int k = 0; k < 32; ++k) acc = fmaf(p2[k], Wp3[k], acc);
        out[0] = 1.f / (1.f + expf(-acc));
    }
}

static inline char* align16(char* p) {
    return (char*)(((uintptr_t)p + 15) & ~(uintptr_t)15);
}

extern "C" void kernel_launch(void* const* d_in, const int* in_sizes, int n_in,
                              void* d_out, int out_size, void* d_ws, size_t ws_size,
                              hipStream_t stream) {
    const float* x   = (const float*)d_in[0];
    const int*   ei  = (const int*)d_in[1];
    const float* ea  = (const float*)d_in[2];
    const float* W1  = (const float*)d_in[3];
    const float* b1  = (const float*)d_in[4];
    const float* W2  = (const float*)d_in[5];
    const float* b2  = (const float*)d_in[6];
    const float* W3  = (const float*)d_in[7];
    const float* b3  = (const float*)d_in[8];
    const float* We1 = (const float*)d_in[9];
    const float* be1 = (const float*)d_in[10];
    const float* We2 = (const float*)d_in[11];
    const float* be2 = (const float*)d_in[12];
    const float* Wp1 = (const float*)d_in[13];
    const float* bp1 = (const float*)d_in[14];
    const float* Wp2 = (const float*)d_in[15];
    const float* bp2 = (const float*)d_in[16];
    const float* Wp3 = (const float*)d_in[17];
    const float* bp3 = (const float*)d_in[18];

    const int N = in_sizes[0] / 6;
    const int E = in_sizes[1] / 2;
    const int nbN = (N + 255) / 256;

    // ---- workspace layout (all 16B-aligned) ----
    char* p = (char*)d_ws;
    double* sums = (double*)p;              p = align16(p + 128 * sizeof(double));
    int* cnt = (int*)p;                     p = align16(p + (size_t)N * 4);
    int* off = (int*)p;                     p = align16(p + ((size_t)N + 1) * 4);
    int* cur = (int*)p;                     p = align16(p + (size_t)N * 4);
    int* bsum = (int*)p;                    p = align16(p + 512 * 4);
    unsigned* adj = (unsigned*)p;           p = align16(p + (size_t)2 * E * 4);
    float* xp = (float*)p;                  p = align16(p + (size_t)N * 6 * 4);
    float* dinv = (float*)p;                p = align16(p + (size_t)N * 4);
    float* bufB = (float*)p;                p = align16(p + (size_t)N * 64 * 4);
    float* bufC = (float*)p;                // N*64 floats; ef6 aliases here
    float* ef6 = bufC;                      // E*6 floats, dead before bufC's first write

    const int TB = 256;
    dim3 blk(TB);

    k_zero<<<dim3(nbN), blk, 0, stream>>>(cnt, sums, N);
    k_hist<<<dim3((E + TB - 1) / TB), blk, 0, stream>>>(ei, cnt, E);
    k_scan1<<<dim3(nbN), blk, 0, stream>>>(cnt, bsum, N);
    k_scan2<<<dim3(1), dim3(512), 0, stream>>>(bsum, nbN, off + N);
    k_scan3<<<dim3(nbN), blk, 0, stream>>>(cnt, bsum, off, cur, N);
    k_edge_mlp<<<dim3((E + TB - 1) / TB), blk, 0, stream>>>(ei, ea, We1, be1, We2, be2,
                                                            ef6, cur, adj, E);
    k_nef_x<<<dim3(nbN), blk, 0, stream>>>(adj, off, ef6, x, xp, dinv, N);

    const unsigned gGather = (unsigned)(((size_t)N * 64 + TB - 1) / TB);
    // layer 1
    k_mm1<<<dim3(1024), blk, 0, stream>>>(xp, W1, bufB, N);
    k_gather<<<dim3(gGather), blk, 0, stream>>>(ei, adj, off, dinv, bufB, bufC, N, E);
    // layer 2
    k_mm<<<dim3(1024), blk, 0, stream>>>(bufC, b1, W2, bufB, N);
    k_gather<<<dim3(gGather), blk, 0, stream>>>(ei, adj, off, dinv, bufB, bufC, N, E);
    // layer 3
    k_mm<<<dim3(1024), blk, 0, stream>>>(bufC, b2, W3, bufB, N);
    k_gather<<<dim3(gGather), blk, 0, stream>>>(ei, adj, off, dinv, bufB, bufC, N, E);

    // pooling (+b3) and head
    k_reduce<<<dim3(512), blk, 0, stream>>>(bufC, b3, sums, N);
    k_head<<<dim3(1), dim3(64), 0, stream>>>(sums, Wp1, bp1, Wp2, bp2, Wp3, bp3,
                                             (float*)d_out, N);
}

// Round 3
// 998.939 us; speedup vs baseline: 2.3311x; 1.5213x over previous
//
#include <hip/hip_runtime.h>
#include <hip/hip_bf16.h>
#include <stdint.h>

__device__ __forceinline__ float rdlane(float v, int l) {
    return __uint_as_float(__builtin_amdgcn_readlane(__float_as_uint(v), l));
}
__device__ __forceinline__ float bf2f(unsigned short u) {
    return __uint_as_float(((unsigned)u) << 16);
}
__device__ __forceinline__ unsigned short f2bf(float f) {
    unsigned u = __float_as_uint(f);
    u += 0x7fffu + ((u >> 16) & 1u);  // RNE
    return (unsigned short)(u >> 16);
}
__device__ __forceinline__ unsigned packbf(float a, float b) {
    return (unsigned)f2bf(a) | ((unsigned)f2bf(b) << 16);
}

// ---------------- zero counters + pooled sums -------------------------------
__global__ void k_zero(int* __restrict__ cntF, int* __restrict__ cntI,
                       double* __restrict__ sums, int n) {
    int i = blockIdx.x * blockDim.x + threadIdx.x;
    if (i < 128) sums[i] = 0.0;
    if (i < n) { cntF[i] = 0; cntI[i] = 0; }
}

// ------- histograms: full incidence (both endpoints) + in-degree (dst) ------
__global__ __launch_bounds__(256) void k_hist(const int* __restrict__ ei,
                                              int* __restrict__ cntF,
                                              int* __restrict__ cntI, int E) {
    int e = blockIdx.x * blockDim.x + threadIdx.x;
    if (e >= E) return;
    int s = ei[e], d = ei[E + e];
    atomicAdd(&cntF[s], 1);
    atomicAdd(&cntF[d], 1);
    atomicAdd(&cntI[d], 1);
}

// ---------------- scan pass 1: per-block totals -----------------------------
__global__ __launch_bounds__(256) void k_scan1(const int* __restrict__ cnt,
                                               int* __restrict__ bsum, int n) {
    __shared__ int l[256];
    int i = blockIdx.x * 256 + threadIdx.x;
    l[threadIdx.x] = (i < n) ? cnt[i] : 0;
    __syncthreads();
    for (int s = 128; s > 0; s >>= 1) {
        if (threadIdx.x < s) l[threadIdx.x] += l[threadIdx.x + s];
        __syncthreads();
    }
    if (threadIdx.x == 0) bsum[blockIdx.x] = l[0];
}

// ---------------- scan pass 2: exclusive scan of block totals (nb<=512) -----
__global__ __launch_bounds__(512) void k_scan2(int* __restrict__ bsum, int nb,
                                               int* __restrict__ offN) {
    __shared__ int l[512];
    int t = threadIdx.x;
    int v = (t < nb) ? bsum[t] : 0;
    l[t] = v;
    __syncthreads();
    for (int s = 1; s < 512; s <<= 1) {
        int tmp = (t >= s) ? l[t - s] : 0;
        __syncthreads();
        l[t] += tmp;
        __syncthreads();
    }
    if (t < nb) bsum[t] = l[t] - v;  // exclusive
    if (t == 511) *offN = l[511];    // grand total
}

// ---------------- scan pass 3: off[i], cursor cur[i] ------------------------
__global__ __launch_bounds__(256) void k_scan3(const int* __restrict__ cnt,
                                               const int* __restrict__ bsum,
                                               int* __restrict__ off, int* __restrict__ cur,
                                               int n) {
    __shared__ int l[256];
    int i = blockIdx.x * 256 + threadIdx.x;
    int v = (i < n) ? cnt[i] : 0;
    l[threadIdx.x] = v;
    __syncthreads();
    for (int s = 1; s < 256; s <<= 1) {
        int tmp = (threadIdx.x >= (unsigned)s) ? l[threadIdx.x - s] : 0;
        __syncthreads();
        l[threadIdx.x] += tmp;
        __syncthreads();
    }
    if (i < n) {
        int excl = l[threadIdx.x] - v + bsum[blockIdx.x];
        off[i] = excl;
        cur[i] = excl;
    }
}

// ------- edge MLP (6 used cols) -> scatter packed bf16 ef into CSR slots ----
// full-CSR slots get the ef row (both endpoints); in-CSR slot gets src id.
__global__ __launch_bounds__(256) void k_edge_mlp(
    const int* __restrict__ ei, const float* __restrict__ ea,
    const float* __restrict__ We1, const float* __restrict__ be1,
    const float* __restrict__ We2, const float* __restrict__ be2,
    unsigned* __restrict__ efp, int* __restrict__ curF,
    int* __restrict__ curI, int* __restrict__ in_src, int E) {
    __shared__ float sWe1[128], sbe1[64], sWe2[64 * 6], sbe2[6];
    int t = threadIdx.x;
    if (t < 128) sWe1[t] = We1[t];
    if (t < 64) {
        sbe1[t] = be1[t];
#pragma unroll
        for (int c = 0; c < 6; ++c) sWe2[t * 6 + c] = We2[t * 64 + c];
    }
    if (t < 6) sbe2[t] = be2[t];
    __syncthreads();

    int e = blockIdx.x * blockDim.x + t;
    if (e >= E) return;
    float a0 = ea[2 * e], a1 = ea[2 * e + 1];
    float acc[6];
#pragma unroll
    for (int c = 0; c < 6; ++c) acc[c] = sbe2[c];
#pragma unroll
    for (int j = 0; j < 64; ++j) {
        float h = fmaf(a0, sWe1[j], fmaf(a1, sWe1[64 + j], sbe1[j]));
        h = fmaxf(h, 0.f);
#pragma unroll
        for (int c = 0; c < 6; ++c) acc[c] = fmaf(h, sWe2[j * 6 + c], acc[c]);
    }
    unsigned u0 = packbf(acc[0], acc[1]);
    unsigned u1 = packbf(acc[2], acc[3]);
    unsigned u2 = packbf(acc[4], acc[5]);

    int s = ei[e], d = ei[E + e];
    int p0 = atomicAdd(&curF[s], 1);
    unsigned* q = efp + (size_t)p0 * 3;
    q[0] = u0; q[1] = u1; q[2] = u2;
    int p1 = atomicAdd(&curF[d], 1);
    q = efp + (size_t)p1 * 3;
    q[0] = u0; q[1] = u1; q[2] = u2;
    int p2 = atomicAdd(&curI[d], 1);
    in_src[p2] = s;
}

// ------- per node: stream own CSR segment of efp -> x'; dinv from in-deg ----
__global__ __launch_bounds__(256) void k_nef_x(
    const int* __restrict__ offF, const unsigned* __restrict__ efp,
    const int* __restrict__ cntI, const float* __restrict__ x,
    float* __restrict__ xp, float* __restrict__ dinv, int n) {
    int i = blockIdx.x * blockDim.x + threadIdx.x;
    if (i >= n) return;
    int b = offF[i], e = offF[i + 1];
    float a0 = 0.f, a1 = 0.f, a2 = 0.f, a3 = 0.f, a4 = 0.f, a5 = 0.f;
    for (int j = b; j < e; ++j) {
        const unsigned* q = efp + (size_t)j * 3;
        unsigned u0 = q[0], u1 = q[1], u2 = q[2];
        a0 += bf2f((unsigned short)u0); a1 += bf2f((unsigned short)(u0 >> 16));
        a2 += bf2f((unsigned short)u1); a3 += bf2f((unsigned short)(u1 >> 16));
        a4 += bf2f((unsigned short)u2); a5 += bf2f((unsigned short)(u2 >> 16));
    }
    float degf = (float)(e - b);
    float inv = 0.5f / fmaxf(degf, 1.f);
    xp[(size_t)i * 6 + 0] = x[(size_t)i * 6 + 0] + a0 * inv;
    xp[(size_t)i * 6 + 1] = x[(size_t)i * 6 + 1] + a1 * inv;
    xp[(size_t)i * 6 + 2] = x[(size_t)i * 6 + 2] + a2 * inv;
    xp[(size_t)i * 6 + 3] = x[(size_t)i * 6 + 3] + a3 * inv;
    xp[(size_t)i * 6 + 4] = x[(size_t)i * 6 + 4] + a4 * inv;
    xp[(size_t)i * 6 + 5] = x[(size_t)i * 6 + 5] + a5 * inv;
    dinv[i] = 1.f / sqrtf(1.f + (float)cntI[i]);
}

// ---------------- layer 1: s1 = bf16(dinv * (x'(N,6) @ W1)) -----------------
__global__ __launch_bounds__(256) void k_mm1(const float* __restrict__ xp,
                                             const float* __restrict__ W1,
                                             const float* __restrict__ dinv,
                                             unsigned short* __restrict__ sOut, int n) {
    int lane = threadIdx.x & 63;
    int wid = (blockIdx.x * blockDim.x + threadIdx.x) >> 6;
    int nw = (gridDim.x * blockDim.x) >> 6;
    float w[6];
#pragma unroll
    for (int c = 0; c < 6; ++c) w[c] = W1[c * 64 + lane];
    for (int i = wid; i < n; i += nw) {
        float xv = (lane < 6) ? xp[(size_t)i * 6 + lane] : 0.f;
        float acc = 0.f;
#pragma unroll
        for (int c = 0; c < 6; ++c) acc = fmaf(rdlane(xv, c), w[c], acc);
        sOut[(size_t)i * 64 + lane] = f2bf(acc * dinv[i]);
    }
}

// ------- layers 2/3: s_out = bf16(dinv * (relu(agg + b_prev) @ W)) ----------
__global__ __launch_bounds__(256) void k_mm(const float* __restrict__ aggin,
                                            const float* __restrict__ bias,
                                            const float* __restrict__ W,
                                            const float* __restrict__ dinv,
                                            unsigned short* __restrict__ sOut, int n) {
    int lane = threadIdx.x & 63;
    int wid = (blockIdx.x * blockDim.x + threadIdx.x) >> 6;
    int nw = (gridDim.x * blockDim.x) >> 6;
    float w[64];
#pragma unroll
    for (int c = 0; c < 64; ++c) w[c] = W[c * 64 + lane];
    float b = bias[lane];
    for (int i = wid; i < n; i += nw) {
        float hv = fmaxf(aggin[(size_t)i * 64 + lane] + b, 0.f);
        float acc = 0.f;
#pragma unroll
        for (int c = 0; c < 64; ++c) acc = fmaf(rdlane(hv, c), w[c], acc);
        sOut[(size_t)i * 64 + lane] = f2bf(acc * dinv[i]);
    }
}

// ------- GCN aggregation: wave/node, lane=feature, bf16 rows, in-CSR --------
__global__ __launch_bounds__(256) void k_gather(const int* __restrict__ in_off,
                                                const int* __restrict__ in_src,
                                                const float* __restrict__ dinv,
                                                const unsigned short* __restrict__ sIn,
                                                float* __restrict__ agg, int n) {
    int w = (int)(((size_t)blockIdx.x * blockDim.x + threadIdx.x) >> 6);
    int lane = threadIdx.x & 63;
    if (w >= n) return;
    float acc = bf2f(sIn[(size_t)w * 64 + lane]);  // self-loop term
    int b = in_off[w], e = in_off[w + 1];
    int j = b;
    for (; j + 8 <= e; j += 8) {
        int s0 = in_src[j], s1 = in_src[j + 1], s2 = in_src[j + 2], s3 = in_src[j + 3];
        int s4 = in_src[j + 4], s5 = in_src[j + 5], s6 = in_src[j + 6], s7 = in_src[j + 7];
        float v0 = bf2f(sIn[(size_t)s0 * 64 + lane]);
        float v1 = bf2f(sIn[(size_t)s1 * 64 + lane]);
        float v2 = bf2f(sIn[(size_t)s2 * 64 + lane]);
        float v3 = bf2f(sIn[(size_t)s3 * 64 + lane]);
        float v4 = bf2f(sIn[(size_t)s4 * 64 + lane]);
        float v5 = bf2f(sIn[(size_t)s5 * 64 + lane]);
        float v6 = bf2f(sIn[(size_t)s6 * 64 + lane]);
        float v7 = bf2f(sIn[(size_t)s7 * 64 + lane]);
        acc += (((v0 + v1) + (v2 + v3)) + ((v4 + v5) + (v6 + v7)));
    }
    for (; j < e; ++j)
        acc += bf2f(sIn[(size_t)in_src[j] * 64 + lane]);
    agg[(size_t)w * 64 + lane] = dinv[w] * acc;
}

// ---------------- pooled sum / sumsq in double ------------------------------
__global__ void k_reduce(const float* __restrict__ agg, const float* __restrict__ b3,
                         double* __restrict__ sums, int n) {
    int t = blockIdx.x * blockDim.x + threadIdx.x;
    int lane = t & 63;
    int r0 = t >> 6;
    int stride = (gridDim.x * blockDim.x) >> 6;
    float b = b3[lane];
    double s = 0.0, s2 = 0.0;
    for (int i = r0; i < n; i += stride) {
        float v = agg[(size_t)i * 64 + lane] + b;
        s += v;
        s2 += (double)v * (double)v;
    }
    unsafeAtomicAdd(&sums[lane], s);
    unsafeAtomicAdd(&sums[64 + lane], s2);
}

// ---------------- head MLP + sigmoid (single block) -------------------------
__global__ void k_head(const double* __restrict__ sums,
                       const float* __restrict__ Wp1, const float* __restrict__ bp1,
                       const float* __restrict__ Wp2, const float* __restrict__ bp2,
                       const float* __restrict__ Wp3, const float* __restrict__ bp3,
                       float* __restrict__ out, int n) {
    __shared__ float comb[192], p1[64], p2[32];
    int t = threadIdx.x;
    if (t < 64) {
        double s = sums[t], s2 = sums[64 + t];
        double m = s / n;
        double var = (s2 - s * s / n) / (double)(n - 1);
        float mf = (float)m;
        float sd = (float)sqrt(var > 0.0 ? var : 0.0);
        comb[t] = mf;
        comb[64 + t] = mf;
        comb[128 + t] = sd;
    }
    __syncthreads();
    if (t < 64) {
        float acc = bp1[t];
        for (int k = 0; k < 192; ++k) acc = fmaf(comb[k], Wp1[k * 64 + t], acc);
        p1[t] = fmaxf(acc, 0.f);
    }
    __syncthreads();
    if (t < 32) {
        float acc = bp2[t];
        for (int k = 0; k < 64; ++k) acc = fmaf(p1[k], Wp2[k * 32 + t], acc);
        p2[t] = fmaxf(acc, 0.f);
    }
    __syncthreads();
    if (t == 0) {
        float acc = bp3[0];
        for (int k = 0; k < 32; ++k) acc = fmaf(p2[k], Wp3[k], acc);
        out[0] = 1.f / (1.f + expf(-acc));
    }
}

static inline char* align16(char* p) {
    return (char*)(((uintptr_t)p + 15) & ~(uintptr_t)15);
}

extern "C" void kernel_launch(void* const* d_in, const int* in_sizes, int n_in,
                              void* d_out, int out_size, void* d_ws, size_t ws_size,
                              hipStream_t stream) {
    const float* x   = (const float*)d_in[0];
    const int*   ei  = (const int*)d_in[1];
    const float* ea  = (const float*)d_in[2];
    const float* W1  = (const float*)d_in[3];
    const float* b1  = (const float*)d_in[4];
    const float* W2  = (const float*)d_in[5];
    const float* b2  = (const float*)d_in[6];
    const float* W3  = (const float*)d_in[7];
    const float* b3  = (const float*)d_in[8];
    const float* We1 = (const float*)d_in[9];
    const float* be1 = (const float*)d_in[10];
    const float* We2 = (const float*)d_in[11];
    const float* be2 = (const float*)d_in[12];
    const float* Wp1 = (const float*)d_in[13];
    const float* bp1 = (const float*)d_in[14];
    const float* Wp2 = (const float*)d_in[15];
    const float* bp2 = (const float*)d_in[16];
    const float* Wp3 = (const float*)d_in[17];
    const float* bp3 = (const float*)d_in[18];

    const int N = in_sizes[0] / 6;
    const int E = in_sizes[1] / 2;
    const int nbN = (N + 255) / 256;

    // ---- workspace layout ----
    char* p = (char*)d_ws;
    double* sums = (double*)p;          p = align16(p + 128 * sizeof(double));
    int* cntF = (int*)p;                p = align16(p + (size_t)N * 4);
    int* offF = (int*)p;                p = align16(p + ((size_t)N + 1) * 4);
    int* curF = (int*)p;                p = align16(p + (size_t)N * 4);
    int* cntI = (int*)p;                p = align16(p + (size_t)N * 4);
    int* offI = (int*)p;                p = align16(p + ((size_t)N + 1) * 4);
    int* curI = (int*)p;                p = align16(p + (size_t)N * 4);
    int* bsumA = (int*)p;               p = align16(p + 512 * 4);
    int* bsumB = (int*)p;               p = align16(p + 512 * 4);
    float* xp = (float*)p;              p = align16(p + (size_t)N * 6 * 4);
    float* dinv = (float*)p;            p = align16(p + (size_t)N * 4);
    int* in_src = (int*)p;              p = align16(p + (size_t)E * 4);
    // union region: efp (2E * 3 uints = 38.4MB) dies before sbuf/agg are born
    char* ubase = p;
    unsigned* efp = (unsigned*)ubase;                       // 2E*12 bytes
    unsigned short* sbuf = (unsigned short*)ubase;          // N*64*2 = 12.8MB
    float* aggbuf = (float*)(ubase + (size_t)N * 64 * 2);   // N*64*4 = 25.6MB

    const int TB = 256;
    dim3 blk(TB);

    k_zero<<<dim3(nbN), blk, 0, stream>>>(cntF, cntI, sums, N);
    k_hist<<<dim3((E + TB - 1) / TB), blk, 0, stream>>>(ei, cntF, cntI, E);
    k_scan1<<<dim3(nbN), blk, 0, stream>>>(cntF, bsumA, N);
    k_scan1<<<dim3(nbN), blk, 0, stream>>>(cntI, bsumB, N);
    k_scan2<<<dim3(1), dim3(512), 0, stream>>>(bsumA, nbN, offF + N);
    k_scan2<<<dim3(1), dim3(512), 0, stream>>>(bsumB, nbN, offI + N);
    k_scan3<<<dim3(nbN), blk, 0, stream>>>(cntF, bsumA, offF, curF, N);
    k_scan3<<<dim3(nbN), blk, 0, stream>>>(cntI, bsumB, offI, curI, N);
    k_edge_mlp<<<dim3((E + TB - 1) / TB), blk, 0, stream>>>(ei, ea, We1, be1, We2, be2,
                                                            efp, curF, curI, in_src, E);
    k_nef_x<<<dim3(nbN), blk, 0, stream>>>(offF, efp, cntI, x, xp, dinv, N);

    const unsigned gGather = (unsigned)(((size_t)N * 64 + TB - 1) / TB);
    // layer 1
    k_mm1<<<dim3(1024), blk, 0, stream>>>(xp, W1, dinv, sbuf, N);
    k_gather<<<dim3(gGather), blk, 0, stream>>>(offI, in_src, dinv, sbuf, aggbuf, N);
    // layer 2
    k_mm<<<dim3(1024), blk, 0, stream>>>(aggbuf, b1, W2, dinv, sbuf, N);
    k_gather<<<dim3(gGather), blk, 0, stream>>>(offI, in_src, dinv, sbuf, aggbuf, N);
    // layer 3
    k_mm<<<dim3(1024), blk, 0, stream>>>(aggbuf, b2, W3, dinv, sbuf, N);
    k_gather<<<dim3(gGather), blk, 0, stream>>>(offI, in_src, dinv, sbuf, aggbuf, N);

    // pooling (+b3) and head
    k_reduce<<<dim3(512), blk, 0, stream>>>(aggbuf, b3, sums, N);
    k_head<<<dim3(1), dim3(64), 0, stream>>>(sums, Wp1, bp1, Wp2, bp2, Wp3, bp3,
                                             (float*)d_out, N);
}

// Round 4
// 755.211 us; speedup vs baseline: 3.0834x; 1.3227x over previous
//
#include <hip/hip_runtime.h>
#include <hip/hip_bf16.h>
#include <stdint.h>

__device__ __forceinline__ float rdlane(float v, int l) {
    return __uint_as_float(__builtin_amdgcn_readlane(__float_as_uint(v), l));
}
__device__ __forceinline__ float bf2f(unsigned short u) {
    return __uint_as_float(((unsigned)u) << 16);
}
__device__ __forceinline__ unsigned short f2bf(float f) {
    unsigned u = __float_as_uint(f);
    u += 0x7fffu + ((u >> 16) & 1u);  // RNE
    return (unsigned short)(u >> 16);
}
__device__ __forceinline__ unsigned packbf(float a, float b) {
    return (unsigned)f2bf(a) | ((unsigned)f2bf(b) << 16);
}

// ---------------- zero counters + pooled sums -------------------------------
__global__ void k_zero(int* __restrict__ cntO, int* __restrict__ cntI,
                       double* __restrict__ sums, int n) {
    int i = blockIdx.x * blockDim.x + threadIdx.x;
    if (i < 128) sums[i] = 0.0;
    if (i < n) { cntO[i] = 0; cntI[i] = 0; }
}

// ------- histogram WITH rank capture: 2 atomics/edge, ranks stream out ------
__global__ __launch_bounds__(256) void k_hist2(const int* __restrict__ ei,
                                               int* __restrict__ cntO,
                                               int* __restrict__ cntI,
                                               int* __restrict__ rankS,
                                               int* __restrict__ rankD, int E) {
    int e = blockIdx.x * blockDim.x + threadIdx.x;
    if (e >= E) return;
    int s = ei[e], d = ei[E + e];
    rankS[e] = atomicAdd(&cntO[s], 1);
    rankD[e] = atomicAdd(&cntI[d], 1);
}

// ---------------- scan pass 1: per-block totals -----------------------------
__global__ __launch_bounds__(256) void k_scan1(const int* __restrict__ cnt,
                                               int* __restrict__ bsum, int n) {
    __shared__ int l[256];
    int i = blockIdx.x * 256 + threadIdx.x;
    l[threadIdx.x] = (i < n) ? cnt[i] : 0;
    __syncthreads();
    for (int s = 128; s > 0; s >>= 1) {
        if (threadIdx.x < s) l[threadIdx.x] += l[threadIdx.x + s];
        __syncthreads();
    }
    if (threadIdx.x == 0) bsum[blockIdx.x] = l[0];
}

// ---------------- scan pass 2: exclusive scan of block totals (nb<=512) -----
__global__ __launch_bounds__(512) void k_scan2(int* __restrict__ bsum, int nb,
                                               int* __restrict__ offN) {
    __shared__ int l[512];
    int t = threadIdx.x;
    int v = (t < nb) ? bsum[t] : 0;
    l[t] = v;
    __syncthreads();
    for (int s = 1; s < 512; s <<= 1) {
        int tmp = (t >= s) ? l[t - s] : 0;
        __syncthreads();
        l[t] += tmp;
        __syncthreads();
    }
    if (t < nb) bsum[t] = l[t] - v;  // exclusive
    if (t == 511) *offN = l[511];    // grand total
}

// ---------------- scan pass 3: exact offsets --------------------------------
__global__ __launch_bounds__(256) void k_scan3off(const int* __restrict__ cnt,
                                                  const int* __restrict__ bsum,
                                                  int* __restrict__ off, int n) {
    __shared__ int l[256];
    int i = blockIdx.x * 256 + threadIdx.x;
    int v = (i < n) ? cnt[i] : 0;
    l[threadIdx.x] = v;
    __syncthreads();
    for (int s = 1; s < 256; s <<= 1) {
        int tmp = (threadIdx.x >= (unsigned)s) ? l[threadIdx.x - s] : 0;
        __syncthreads();
        l[threadIdx.x] += tmp;
        __syncthreads();
    }
    if (i < n) off[i] = l[threadIdx.x] - v + bsum[blockIdx.x];
}

// ------- edge MLP (6 used cols only) -> STREAMING packed bf16 ef ------------
__global__ __launch_bounds__(256) void k_edge_mlp(
    const float* __restrict__ ea,
    const float* __restrict__ We1, const float* __restrict__ be1,
    const float* __restrict__ We2, const float* __restrict__ be2,
    unsigned* __restrict__ efp, int E) {
    __shared__ float sWe1[128], sbe1[64], sWe2[64 * 6], sbe2[6];
    int t = threadIdx.x;
    if (t < 128) sWe1[t] = We1[t];
    if (t < 64) {
        sbe1[t] = be1[t];
#pragma unroll
        for (int c = 0; c < 6; ++c) sWe2[t * 6 + c] = We2[t * 64 + c];
    }
    if (t < 6) sbe2[t] = be2[t];
    __syncthreads();

    int e = blockIdx.x * blockDim.x + t;
    if (e >= E) return;
    float a0 = ea[2 * e], a1 = ea[2 * e + 1];
    float acc[6];
#pragma unroll
    for (int c = 0; c < 6; ++c) acc[c] = sbe2[c];
#pragma unroll
    for (int j = 0; j < 64; ++j) {
        float h = fmaf(a0, sWe1[j], fmaf(a1, sWe1[64 + j], sbe1[j]));
        h = fmaxf(h, 0.f);
#pragma unroll
        for (int c = 0; c < 6; ++c) acc[c] = fmaf(h, sWe2[j * 6 + c], acc[c]);
    }
    unsigned* q = efp + (size_t)e * 3;
    q[0] = packbf(acc[0], acc[1]);
    q[1] = packbf(acc[2], acc[3]);
    q[2] = packbf(acc[4], acc[5]);
}

// ------- CSR placement: ZERO atomics, 2 scattered stores/edge ---------------
__global__ __launch_bounds__(256) void k_place(const int* __restrict__ ei,
                                               const int* __restrict__ rankS,
                                               const int* __restrict__ rankD,
                                               const int* __restrict__ offO,
                                               const int* __restrict__ offI,
                                               unsigned* __restrict__ out_eid,
                                               uint2* __restrict__ in_pk, int E) {
    int e = blockIdx.x * blockDim.x + threadIdx.x;
    if (e >= E) return;
    int s = ei[e], d = ei[E + e];
    out_eid[offO[s] + rankS[e]] = (unsigned)e;
    in_pk[offI[d] + rankD[e]] = make_uint2((unsigned)s, (unsigned)e);
}

// ------- per node: nef = sum ef over out+in segments; x'; dinv --------------
__global__ __launch_bounds__(256) void k_nef_x(
    const int* __restrict__ offO, const unsigned* __restrict__ out_eid,
    const int* __restrict__ offI, const uint2* __restrict__ in_pk,
    const unsigned* __restrict__ efp, const float* __restrict__ x,
    float* __restrict__ xp, float* __restrict__ dinv, int n) {
    int i = blockIdx.x * blockDim.x + threadIdx.x;
    if (i >= n) return;
    int bo = offO[i], eo = offO[i + 1];
    int bi = offI[i], eiN = offI[i + 1];
    float a0 = 0.f, a1 = 0.f, a2 = 0.f, a3 = 0.f, a4 = 0.f, a5 = 0.f;
    for (int j = bo; j < eo; ++j) {
        const unsigned* q = efp + (size_t)out_eid[j] * 3;
        unsigned u0 = q[0], u1 = q[1], u2 = q[2];
        a0 += bf2f((unsigned short)u0); a1 += bf2f((unsigned short)(u0 >> 16));
        a2 += bf2f((unsigned short)u1); a3 += bf2f((unsigned short)(u1 >> 16));
        a4 += bf2f((unsigned short)u2); a5 += bf2f((unsigned short)(u2 >> 16));
    }
    for (int j = bi; j < eiN; ++j) {
        const unsigned* q = efp + (size_t)in_pk[j].y * 3;
        unsigned u0 = q[0], u1 = q[1], u2 = q[2];
        a0 += bf2f((unsigned short)u0); a1 += bf2f((unsigned short)(u0 >> 16));
        a2 += bf2f((unsigned short)u1); a3 += bf2f((unsigned short)(u1 >> 16));
        a4 += bf2f((unsigned short)u2); a5 += bf2f((unsigned short)(u2 >> 16));
    }
    int indeg = eiN - bi;
    float degf = (float)((eo - bo) + indeg);
    float inv = 0.5f / fmaxf(degf, 1.f);
    xp[(size_t)i * 6 + 0] = x[(size_t)i * 6 + 0] + a0 * inv;
    xp[(size_t)i * 6 + 1] = x[(size_t)i * 6 + 1] + a1 * inv;
    xp[(size_t)i * 6 + 2] = x[(size_t)i * 6 + 2] + a2 * inv;
    xp[(size_t)i * 6 + 3] = x[(size_t)i * 6 + 3] + a3 * inv;
    xp[(size_t)i * 6 + 4] = x[(size_t)i * 6 + 4] + a4 * inv;
    xp[(size_t)i * 6 + 5] = x[(size_t)i * 6 + 5] + a5 * inv;
    dinv[i] = 1.f / sqrtf(1.f + (float)indeg);
}

// ---------------- layer 1: s1 = bf16(dinv * (x'(N,6) @ W1)) -----------------
__global__ __launch_bounds__(256) void k_mm1(const float* __restrict__ xp,
                                             const float* __restrict__ W1,
                                             const float* __restrict__ dinv,
                                             unsigned short* __restrict__ sOut, int n) {
    int lane = threadIdx.x & 63;
    int wid = (blockIdx.x * blockDim.x + threadIdx.x) >> 6;
    int nw = (gridDim.x * blockDim.x) >> 6;
    float w[6];
#pragma unroll
    for (int c = 0; c < 6; ++c) w[c] = W1[c * 64 + lane];
    for (int i = wid; i < n; i += nw) {
        float xv = (lane < 6) ? xp[(size_t)i * 6 + lane] : 0.f;
        float acc = 0.f;
#pragma unroll
        for (int c = 0; c < 6; ++c) acc = fmaf(rdlane(xv, c), w[c], acc);
        sOut[(size_t)i * 64 + lane] = f2bf(acc * dinv[i]);
    }
}

// ------- FUSED: gather layer L, relu(+bias), @W, scale, bf16 out ------------
__global__ __launch_bounds__(256) void k_gathermm(
    const int* __restrict__ offI, const uint2* __restrict__ in_pk,
    const float* __restrict__ dinv, const unsigned short* __restrict__ sIn,
    const float* __restrict__ bias, const float* __restrict__ W,
    unsigned short* __restrict__ sOut, int n) {
    int lane = threadIdx.x & 63;
    int wid = (blockIdx.x * blockDim.x + threadIdx.x) >> 6;
    int nw = (gridDim.x * blockDim.x) >> 6;
    float w[64];
#pragma unroll
    for (int c = 0; c < 64; ++c) w[c] = W[c * 64 + lane];
    float b = bias[lane];
    for (int i = wid; i < n; i += nw) {
        float acc = bf2f(sIn[(size_t)i * 64 + lane]);  // self-loop
        int b0 = offI[i], e0 = offI[i + 1];
        int j = b0;
        for (; j + 4 <= e0; j += 4) {
            uint2 p0 = in_pk[j], p1 = in_pk[j + 1], p2 = in_pk[j + 2], p3 = in_pk[j + 3];
            float v0 = bf2f(sIn[(size_t)p0.x * 64 + lane]);
            float v1 = bf2f(sIn[(size_t)p1.x * 64 + lane]);
            float v2 = bf2f(sIn[(size_t)p2.x * 64 + lane]);
            float v3 = bf2f(sIn[(size_t)p3.x * 64 + lane]);
            acc += (v0 + v1) + (v2 + v3);
        }
        for (; j < e0; ++j)
            acc += bf2f(sIn[(size_t)in_pk[j].x * 64 + lane]);
        float dv = dinv[i];
        float hv = fmaxf(fmaf(acc, dv, b), 0.f);  // relu(agg + bias_prev)
        float o = 0.f;
#pragma unroll
        for (int c = 0; c < 64; ++c) o = fmaf(rdlane(hv, c), w[c], o);
        sOut[(size_t)i * 64 + lane] = f2bf(o * dv);
    }
}

// ------- FUSED final: gather layer 3, +b3, pooled sum/sumsq (double) --------
__global__ __launch_bounds__(256) void k_gatherreduce(
    const int* __restrict__ offI, const uint2* __restrict__ in_pk,
    const float* __restrict__ dinv, const unsigned short* __restrict__ sIn,
    const float* __restrict__ b3, double* __restrict__ sums, int n) {
    int lane = threadIdx.x & 63;
    int wv = threadIdx.x >> 6;
    int wid = (blockIdx.x * blockDim.x + threadIdx.x) >> 6;
    int nw = (gridDim.x * blockDim.x) >> 6;
    float b = b3[lane];
    double s = 0.0, s2 = 0.0;
    for (int i = wid; i < n; i += nw) {
        float acc = bf2f(sIn[(size_t)i * 64 + lane]);
        int b0 = offI[i], e0 = offI[i + 1];
        int j = b0;
        for (; j + 4 <= e0; j += 4) {
            uint2 p0 = in_pk[j], p1 = in_pk[j + 1], p2 = in_pk[j + 2], p3 = in_pk[j + 3];
            float v0 = bf2f(sIn[(size_t)p0.x * 64 + lane]);
            float v1 = bf2f(sIn[(size_t)p1.x * 64 + lane]);
            float v2 = bf2f(sIn[(size_t)p2.x * 64 + lane]);
            float v3 = bf2f(sIn[(size_t)p3.x * 64 + lane]);
            acc += (v0 + v1) + (v2 + v3);
        }
        for (; j < e0; ++j)
            acc += bf2f(sIn[(size_t)in_pk[j].x * 64 + lane]);
        float v = fmaf(acc, dinv[i], b);  // layer-3 out + b3 (no relu)
        s += v;
        s2 += (double)v * (double)v;
    }
    __shared__ double sh[4 * 128];
    sh[wv * 128 + lane] = s;
    sh[wv * 128 + 64 + lane] = s2;
    __syncthreads();
    if (wv == 0) {
        double a = sh[lane] + sh[128 + lane] + sh[256 + lane] + sh[384 + lane];
        double c = sh[64 + lane] + sh[192 + lane] + sh[320 + lane] + sh[448 + lane];
        unsafeAtomicAdd(&sums[lane], a);
        unsafeAtomicAdd(&sums[64 + lane], c);
    }
}

// ---------------- head MLP + sigmoid (single block) -------------------------
__global__ void k_head(const double* __restrict__ sums,
                       const float* __restrict__ Wp1, const float* __restrict__ bp1,
                       const float* __restrict__ Wp2, const float* __restrict__ bp2,
                       const float* __restrict__ Wp3, const float* __restrict__ bp3,
                       float* __restrict__ out, int n) {
    __shared__ float comb[192], p1[64], p2[32];
    int t = threadIdx.x;
    if (t < 64) {
        double s = sums[t], s2 = sums[64 + t];
        double m = s / n;
        double var = (s2 - s * s / n) / (double)(n - 1);
        float mf = (float)m;
        float sd = (float)sqrt(var > 0.0 ? var : 0.0);
        comb[t] = mf;
        comb[64 + t] = mf;
        comb[128 + t] = sd;
    }
    __syncthreads();
    if (t < 64) {
        float acc = bp1[t];
        for (int k = 0; k < 192; ++k) acc = fmaf(comb[k], Wp1[k * 64 + t], acc);
        p1[t] = fmaxf(acc, 0.f);
    }
    __syncthreads();
    if (t < 32) {
        float acc = bp2[t];
        for (int k = 0; k < 64; ++k) acc = fmaf(p1[k], Wp2[k * 32 + t], acc);
        p2[t] = fmaxf(acc, 0.f);
    }
    __syncthreads();
    if (t == 0) {
        float acc = bp3[0];
        for (int k = 0; k < 32; ++k) acc = fmaf(p2[k], Wp3[k], acc);
        out[0] = 1.f / (1.f + expf(-acc));
    }
}

static inline char* align16(char* p) {
    return (char*)(((uintptr_t)p + 15) & ~(uintptr_t)15);
}

extern "C" void kernel_launch(void* const* d_in, const int* in_sizes, int n_in,
                              void* d_out, int out_size, void* d_ws, size_t ws_size,
                              hipStream_t stream) {
    const float* x   = (const float*)d_in[0];
    const int*   ei  = (const int*)d_in[1];
    const float* ea  = (const float*)d_in[2];
    const float* W1  = (const float*)d_in[3];
    const float* b1  = (const float*)d_in[4];
    const float* W2  = (const float*)d_in[5];
    const float* b2  = (const float*)d_in[6];
    const float* W3  = (const float*)d_in[7];
    const float* b3  = (const float*)d_in[8];
    const float* We1 = (const float*)d_in[9];
    const float* be1 = (const float*)d_in[10];
    const float* We2 = (const float*)d_in[11];
    const float* be2 = (const float*)d_in[12];
    const float* Wp1 = (const float*)d_in[13];
    const float* bp1 = (const float*)d_in[14];
    const float* Wp2 = (const float*)d_in[15];
    const float* bp2 = (const float*)d_in[16];
    const float* Wp3 = (const float*)d_in[17];
    const float* bp3 = (const float*)d_in[18];

    const int N = in_sizes[0] / 6;
    const int E = in_sizes[1] / 2;
    const int nbN = (N + 255) / 256;
    const int nbE = (E + 255) / 256;
    const size_t SB = (size_t)N * 64 * 2;  // one bf16 table = 12.8MB (>= E*4)

    // ---- workspace layout (~68 MB) ----
    char* p = (char*)d_ws;
    double* sums = (double*)p;          p = align16(p + 128 * sizeof(double));
    int* cntO = (int*)p;                p = align16(p + (size_t)N * 4);
    int* cntI = (int*)p;                p = align16(p + (size_t)N * 4);
    int* offO = (int*)p;                p = align16(p + ((size_t)N + 1) * 4);
    int* offI = (int*)p;                p = align16(p + ((size_t)N + 1) * 4);
    int* bsumA = (int*)p;               p = align16(p + 512 * 4);
    int* bsumB = (int*)p;               p = align16(p + 512 * 4);
    float* xp = (float*)p;              p = align16(p + (size_t)N * 6 * 4);
    float* dinv = (float*)p;            p = align16(p + (size_t)N * 4);
    uint2* in_pk = (uint2*)p;           p = align16(p + (size_t)E * 8);
    // U1: rankS/rankD die after k_place; reborn as bf16 ping-pong tables
    char* u1 = p;                       p = align16(p + 2 * SB);
    int* rankS = (int*)u1;
    int* rankD = (int*)(u1 + SB);
    unsigned short* sbufA = (unsigned short*)u1;
    unsigned short* sbufB = (unsigned short*)(u1 + SB);
    // U2: efp + out_eid die after k_nef_x
    char* u2 = p;
    unsigned* efp = (unsigned*)u2;
    unsigned* out_eid = (unsigned*)(u2 + (size_t)E * 12);

    const int TB = 256;
    dim3 blk(TB);

    k_zero<<<dim3(nbN), blk, 0, stream>>>(cntO, cntI, sums, N);
    k_hist2<<<dim3(nbE), blk, 0, stream>>>(ei, cntO, cntI, rankS, rankD, E);
    k_scan1<<<dim3(nbN), blk, 0, stream>>>(cntO, bsumA, N);
    k_scan1<<<dim3(nbN), blk, 0, stream>>>(cntI, bsumB, N);
    k_scan2<<<dim3(1), dim3(512), 0, stream>>>(bsumA, nbN, offO + N);
    k_scan2<<<dim3(1), dim3(512), 0, stream>>>(bsumB, nbN, offI + N);
    k_scan3off<<<dim3(nbN), blk, 0, stream>>>(cntO, bsumA, offO, N);
    k_scan3off<<<dim3(nbN), blk, 0, stream>>>(cntI, bsumB, offI, N);
    k_edge_mlp<<<dim3(nbE), blk, 0, stream>>>(ea, We1, be1, We2, be2, efp, E);
    k_place<<<dim3(nbE), blk, 0, stream>>>(ei, rankS, rankD, offO, offI, out_eid, in_pk, E);
    k_nef_x<<<dim3(nbN), blk, 0, stream>>>(offO, out_eid, offI, in_pk, efp, x, xp, dinv, N);

    // layer 1 matmul (sbufA aliases rankS — dead after k_place)
    k_mm1<<<dim3(1024), blk, 0, stream>>>(xp, W1, dinv, sbufA, N);
    // layers 2,3 fused gather+mm; final fused gather+reduce
    k_gathermm<<<dim3(2048), blk, 0, stream>>>(offI, in_pk, dinv, sbufA, b1, W2, sbufB, N);
    k_gathermm<<<dim3(2048), blk, 0, stream>>>(offI, in_pk, dinv, sbufB, b2, W3, sbufA, N);
    k_gatherreduce<<<dim3(512), blk, 0, stream>>>(offI, in_pk, dinv, sbufA, b3, sums, N);
    k_head<<<dim3(1), dim3(64), 0, stream>>>(sums, Wp1, bp1, Wp2, bp2, Wp3, bp3,
                                             (float*)d_out, N);
}

// Round 5
// 585.941 us; speedup vs baseline: 3.9742x; 1.2889x over previous
//
#include <hip/hip_runtime.h>
#include <hip/hip_bf16.h>
#include <stdint.h>

__device__ __forceinline__ float rdlane(float v, int l) {
    return __uint_as_float(__builtin_amdgcn_readlane(__float_as_uint(v), l));
}
__device__ __forceinline__ float bf2f(unsigned short u) {
    return __uint_as_float(((unsigned)u) << 16);
}
__device__ __forceinline__ unsigned short f2bf(float f) {
    unsigned u = __float_as_uint(f);
    u += 0x7fffu + ((u >> 16) & 1u);  // RNE
    return (unsigned short)(u >> 16);
}
__device__ __forceinline__ unsigned packbf(float a, float b) {
    return (unsigned)f2bf(a) | ((unsigned)f2bf(b) << 16);
}

// ---------------- zero counters + pooled sums -------------------------------
__global__ void k_zero(int* __restrict__ cntO, int* __restrict__ cntI,
                       double* __restrict__ sums, int n) {
    int i = blockIdx.x * blockDim.x + threadIdx.x;
    if (i < 128) sums[i] = 0.0;
    if (i < n) { cntO[i] = 0; cntI[i] = 0; }
}

// ------- FUSED front: edge MLP (VALU) hides under 2 rank atomics/edge -------
__global__ __launch_bounds__(256) void k_front(
    const int* __restrict__ ei, const float* __restrict__ ea,
    const float* __restrict__ We1, const float* __restrict__ be1,
    const float* __restrict__ We2, const float* __restrict__ be2,
    unsigned* __restrict__ efp, int* __restrict__ cntO, int* __restrict__ cntI,
    int* __restrict__ rankS, int* __restrict__ rankD, int E) {
    __shared__ float sWe1[128], sbe1[64], sWe2[64 * 6], sbe2[6];
    int t = threadIdx.x;
    if (t < 128) sWe1[t] = We1[t];
    if (t < 64) {
        sbe1[t] = be1[t];
#pragma unroll
        for (int c = 0; c < 6; ++c) sWe2[t * 6 + c] = We2[t * 64 + c];
    }
    if (t < 6) sbe2[t] = be2[t];
    __syncthreads();

    int e = blockIdx.x * blockDim.x + t;
    if (e >= E) return;

    int s = ei[e], d = ei[E + e];
    // issue atomics early; MLP compute below overlaps the RMW round-trip
    int rs = atomicAdd(&cntO[s], 1);
    int rd = atomicAdd(&cntI[d], 1);

    float a0 = ea[2 * e], a1 = ea[2 * e + 1];
    float acc[6];
#pragma unroll
    for (int c = 0; c < 6; ++c) acc[c] = sbe2[c];
#pragma unroll
    for (int j = 0; j < 64; ++j) {
        float h = fmaf(a0, sWe1[j], fmaf(a1, sWe1[64 + j], sbe1[j]));
        h = fmaxf(h, 0.f);
#pragma unroll
        for (int c = 0; c < 6; ++c) acc[c] = fmaf(h, sWe2[j * 6 + c], acc[c]);
    }
    unsigned* q = efp + (size_t)e * 3;
    q[0] = packbf(acc[0], acc[1]);
    q[1] = packbf(acc[2], acc[3]);
    q[2] = packbf(acc[4], acc[5]);
    rankS[e] = rs;
    rankD[e] = rd;
}

// ---------------- scan pass 1: per-block totals -----------------------------
__global__ __launch_bounds__(256) void k_scan1(const int* __restrict__ cnt,
                                               int* __restrict__ bsum, int n) {
    __shared__ int l[256];
    int i = blockIdx.x * 256 + threadIdx.x;
    l[threadIdx.x] = (i < n) ? cnt[i] : 0;
    __syncthreads();
    for (int s = 128; s > 0; s >>= 1) {
        if (threadIdx.x < s) l[threadIdx.x] += l[threadIdx.x + s];
        __syncthreads();
    }
    if (threadIdx.x == 0) bsum[blockIdx.x] = l[0];
}

// ---------------- scan pass 2: exclusive scan of block totals (nb<=512) -----
__global__ __launch_bounds__(512) void k_scan2(int* __restrict__ bsum, int nb,
                                               int* __restrict__ offN) {
    __shared__ int l[512];
    int t = threadIdx.x;
    int v = (t < nb) ? bsum[t] : 0;
    l[t] = v;
    __syncthreads();
    for (int s = 1; s < 512; s <<= 1) {
        int tmp = (t >= s) ? l[t - s] : 0;
        __syncthreads();
        l[t] += tmp;
        __syncthreads();
    }
    if (t < nb) bsum[t] = l[t] - v;  // exclusive
    if (t == 511) *offN = l[511];    // grand total
}

// ---------------- scan pass 3: exact offsets --------------------------------
__global__ __launch_bounds__(256) void k_scan3off(const int* __restrict__ cnt,
                                                  const int* __restrict__ bsum,
                                                  int* __restrict__ off, int n) {
    __shared__ int l[256];
    int i = blockIdx.x * 256 + threadIdx.x;
    int v = (i < n) ? cnt[i] : 0;
    l[threadIdx.x] = v;
    __syncthreads();
    for (int s = 1; s < 256; s <<= 1) {
        int tmp = (threadIdx.x >= (unsigned)s) ? l[threadIdx.x - s] : 0;
        __syncthreads();
        l[threadIdx.x] += tmp;
        __syncthreads();
    }
    if (i < n) off[i] = l[threadIdx.x] - v + bsum[blockIdx.x];
}

// ------- CSR placement: ZERO atomics, 2 scattered stores/edge ---------------
__global__ __launch_bounds__(256) void k_place(const int* __restrict__ ei,
                                               const int* __restrict__ rankS,
                                               const int* __restrict__ rankD,
                                               const int* __restrict__ offO,
                                               const int* __restrict__ offI,
                                               unsigned* __restrict__ out_eid,
                                               uint2* __restrict__ in_pk, int E) {
    int e = blockIdx.x * blockDim.x + threadIdx.x;
    if (e >= E) return;
    int s = ei[e], d = ei[E + e];
    out_eid[offO[s] + rankS[e]] = (unsigned)e;
    in_pk[offI[d] + rankD[e]] = make_uint2((unsigned)s, (unsigned)e);
}

// ------- per node: nef = sum ef over out+in segments; x'; dinv --------------
__global__ __launch_bounds__(256) void k_nef_x(
    const int* __restrict__ offO, const unsigned* __restrict__ out_eid,
    const int* __restrict__ offI, const uint2* __restrict__ in_pk,
    const unsigned* __restrict__ efp, const float* __restrict__ x,
    float* __restrict__ xp, float* __restrict__ dinv, int n) {
    int i = blockIdx.x * blockDim.x + threadIdx.x;
    if (i >= n) return;
    int bo = offO[i], eo = offO[i + 1];
    int bi = offI[i], eiN = offI[i + 1];
    float a0 = 0.f, a1 = 0.f, a2 = 0.f, a3 = 0.f, a4 = 0.f, a5 = 0.f;
    for (int j = bo; j < eo; ++j) {
        const unsigned* q = efp + (size_t)out_eid[j] * 3;
        unsigned u0 = q[0], u1 = q[1], u2 = q[2];
        a0 += bf2f((unsigned short)u0); a1 += bf2f((unsigned short)(u0 >> 16));
        a2 += bf2f((unsigned short)u1); a3 += bf2f((unsigned short)(u1 >> 16));
        a4 += bf2f((unsigned short)u2); a5 += bf2f((unsigned short)(u2 >> 16));
    }
    for (int j = bi; j < eiN; ++j) {
        const unsigned* q = efp + (size_t)in_pk[j].y * 3;
        unsigned u0 = q[0], u1 = q[1], u2 = q[2];
        a0 += bf2f((unsigned short)u0); a1 += bf2f((unsigned short)(u0 >> 16));
        a2 += bf2f((unsigned short)u1); a3 += bf2f((unsigned short)(u1 >> 16));
        a4 += bf2f((unsigned short)u2); a5 += bf2f((unsigned short)(u2 >> 16));
    }
    int indeg = eiN - bi;
    float degf = (float)((eo - bo) + indeg);
    float inv = 0.5f / fmaxf(degf, 1.f);
    xp[(size_t)i * 6 + 0] = x[(size_t)i * 6 + 0] + a0 * inv;
    xp[(size_t)i * 6 + 1] = x[(size_t)i * 6 + 1] + a1 * inv;
    xp[(size_t)i * 6 + 2] = x[(size_t)i * 6 + 2] + a2 * inv;
    xp[(size_t)i * 6 + 3] = x[(size_t)i * 6 + 3] + a3 * inv;
    xp[(size_t)i * 6 + 4] = x[(size_t)i * 6 + 4] + a4 * inv;
    xp[(size_t)i * 6 + 5] = x[(size_t)i * 6 + 5] + a5 * inv;
    dinv[i] = 1.f / sqrtf(1.f + (float)indeg);
}

// ---------------- layer 1: s1 = bf16(dinv * (x'(N,6) @ W1)) -----------------
__global__ __launch_bounds__(256) void k_mm1(const float* __restrict__ xp,
                                             const float* __restrict__ W1,
                                             const float* __restrict__ dinv,
                                             unsigned short* __restrict__ sOut, int n) {
    int lane = threadIdx.x & 63;
    int wid = (blockIdx.x * blockDim.x + threadIdx.x) >> 6;
    int nw = (gridDim.x * blockDim.x) >> 6;
    float w[6];
#pragma unroll
    for (int c = 0; c < 6; ++c) w[c] = W1[c * 64 + lane];
    for (int i = wid; i < n; i += nw) {
        float xv = (lane < 6) ? xp[(size_t)i * 6 + lane] : 0.f;
        float acc = 0.f;
#pragma unroll
        for (int c = 0; c < 6; ++c) acc = fmaf(rdlane(xv, c), w[c], acc);
        sOut[(size_t)i * 64 + lane] = f2bf(acc * dinv[i]);
    }
}

// ------- FUSED gather+mm, 4-row vectorized: 16 lanes x ushort4 per row ------
// lane = 16*grp + sub; group g gathers rows j = b0+g, b0+g+4, ...
__global__ __launch_bounds__(256) void k_gathermm(
    const int* __restrict__ offI, const uint2* __restrict__ in_pk,
    const float* __restrict__ dinv, const unsigned short* __restrict__ sIn,
    const float* __restrict__ bias, const float* __restrict__ W,
    unsigned short* __restrict__ sOut, int n) {
    int lane = threadIdx.x & 63;
    int sub = lane & 15, grp = lane >> 4;
    int wid = (blockIdx.x * blockDim.x + threadIdx.x) >> 6;
    int nw = (gridDim.x * blockDim.x) >> 6;
    float w[64];
#pragma unroll
    for (int c = 0; c < 64; ++c) w[c] = W[c * 64 + lane];
    float4 bb = ((const float4*)bias)[sub];

    for (int i = wid; i < n; i += nw) {
        // self-loop term: counted once (group 0 only)
        ushort4 sv = *(const ushort4*)(sIn + (size_t)i * 64 + sub * 4);
        float a0, a1, a2, a3;
        if (grp == 0) { a0 = bf2f(sv.x); a1 = bf2f(sv.y); a2 = bf2f(sv.z); a3 = bf2f(sv.w); }
        else { a0 = a1 = a2 = a3 = 0.f; }
        int b0 = offI[i], e0 = offI[i + 1];
#pragma unroll 2
        for (int j = b0 + grp; j < e0; j += 4) {
            unsigned src = in_pk[j].x;
            ushort4 v = *(const ushort4*)(sIn + (size_t)src * 64 + sub * 4);
            a0 += bf2f(v.x); a1 += bf2f(v.y); a2 += bf2f(v.z); a3 += bf2f(v.w);
        }
        // combine the 4 lane-groups
        a0 += __shfl_xor(a0, 16); a1 += __shfl_xor(a1, 16);
        a2 += __shfl_xor(a2, 16); a3 += __shfl_xor(a3, 16);
        a0 += __shfl_xor(a0, 32); a1 += __shfl_xor(a1, 32);
        a2 += __shfl_xor(a2, 32); a3 += __shfl_xor(a3, 32);

        float dv = dinv[i];
        float h0 = fmaxf(fmaf(a0, dv, bb.x), 0.f);
        float h1 = fmaxf(fmaf(a1, dv, bb.y), 0.f);
        float h2 = fmaxf(fmaf(a2, dv, bb.z), 0.f);
        float h3 = fmaxf(fmaf(a3, dv, bb.w), 0.f);
        float o = 0.f;
#pragma unroll
        for (int g = 0; g < 16; ++g) {
            o = fmaf(rdlane(h0, g), w[g * 4 + 0], o);
            o = fmaf(rdlane(h1, g), w[g * 4 + 1], o);
            o = fmaf(rdlane(h2, g), w[g * 4 + 2], o);
            o = fmaf(rdlane(h3, g), w[g * 4 + 3], o);
        }
        sOut[(size_t)i * 64 + lane] = f2bf(o * dv);
    }
}

// ------- FUSED final gather + b3 + pooled sum/sumsq, 4-row vectorized -------
__global__ __launch_bounds__(256) void k_gatherreduce(
    const int* __restrict__ offI, const uint2* __restrict__ in_pk,
    const float* __restrict__ dinv, const unsigned short* __restrict__ sIn,
    const float* __restrict__ b3, double* __restrict__ sums, int n) {
    int lane = threadIdx.x & 63;
    int sub = lane & 15, grp = lane >> 4;
    int wv = threadIdx.x >> 6;
    int wid = (blockIdx.x * blockDim.x + threadIdx.x) >> 6;
    int nw = (gridDim.x * blockDim.x) >> 6;
    float4 bb = ((const float4*)b3)[sub];
    double s0 = 0.0, s1 = 0.0, s2_ = 0.0, s3 = 0.0;
    double q0 = 0.0, q1 = 0.0, q2 = 0.0, q3 = 0.0;

    for (int i = wid; i < n; i += nw) {
        ushort4 sv = *(const ushort4*)(sIn + (size_t)i * 64 + sub * 4);
        float a0, a1, a2, a3;
        if (grp == 0) { a0 = bf2f(sv.x); a1 = bf2f(sv.y); a2 = bf2f(sv.z); a3 = bf2f(sv.w); }
        else { a0 = a1 = a2 = a3 = 0.f; }
        int b0 = offI[i], e0 = offI[i + 1];
#pragma unroll 2
        for (int j = b0 + grp; j < e0; j += 4) {
            unsigned src = in_pk[j].x;
            ushort4 v = *(const ushort4*)(sIn + (size_t)src * 64 + sub * 4);
            a0 += bf2f(v.x); a1 += bf2f(v.y); a2 += bf2f(v.z); a3 += bf2f(v.w);
        }
        a0 += __shfl_xor(a0, 16); a1 += __shfl_xor(a1, 16);
        a2 += __shfl_xor(a2, 16); a3 += __shfl_xor(a3, 16);
        a0 += __shfl_xor(a0, 32); a1 += __shfl_xor(a1, 32);
        a2 += __shfl_xor(a2, 32); a3 += __shfl_xor(a3, 32);

        float dv = dinv[i];
        float v0 = fmaf(a0, dv, bb.x);
        float v1 = fmaf(a1, dv, bb.y);
        float v2 = fmaf(a2, dv, bb.z);
        float v3 = fmaf(a3, dv, bb.w);
        s0 += v0; s1 += v1; s2_ += v2; s3 += v3;
        q0 += (double)v0 * v0; q1 += (double)v1 * v1;
        q2 += (double)v2 * v2; q3 += (double)v3 * v3;
    }
    // block reduce: only grp-0 lanes hold meaningful (duplicated) sums
    __shared__ double shS[4 * 64], shQ[4 * 64];
    if (grp == 0) {
#pragma unroll
        for (int k = 0; k < 4; ++k) {
            double sk = (k == 0) ? s0 : (k == 1) ? s1 : (k == 2) ? s2_ : s3;
            double qk = (k == 0) ? q0 : (k == 1) ? q1 : (k == 2) ? q2 : q3;
            shS[wv * 64 + sub * 4 + k] = sk;
            shQ[wv * 64 + sub * 4 + k] = qk;
        }
    }
    __syncthreads();
    if (wv == 0) {
        double a = shS[lane] + shS[64 + lane] + shS[128 + lane] + shS[192 + lane];
        double c = shQ[lane] + shQ[64 + lane] + shQ[128 + lane] + shQ[192 + lane];
        unsafeAtomicAdd(&sums[lane], a);
        unsafeAtomicAdd(&sums[64 + lane], c);
    }
}

// ---------------- head MLP + sigmoid (single block) -------------------------
__global__ void k_head(const double* __restrict__ sums,
                       const float* __restrict__ Wp1, const float* __restrict__ bp1,
                       const float* __restrict__ Wp2, const float* __restrict__ bp2,
                       const float* __restrict__ Wp3, const float* __restrict__ bp3,
                       float* __restrict__ out, int n) {
    __shared__ float comb[192], p1[64], p2[32];
    int t = threadIdx.x;
    if (t < 64) {
        double s = sums[t], s2 = sums[64 + t];
        double m = s / n;
        double var = (s2 - s * s / n) / (double)(n - 1);
        float mf = (float)m;
        float sd = (float)sqrt(var > 0.0 ? var : 0.0);
        comb[t] = mf;
        comb[64 + t] = mf;
        comb[128 + t] = sd;
    }
    __syncthreads();
    if (t < 64) {
        float acc = bp1[t];
        for (int k = 0; k < 192; ++k) acc = fmaf(comb[k], Wp1[k * 64 + t], acc);
        p1[t] = fmaxf(acc, 0.f);
    }
    __syncthreads();
    if (t < 32) {
        float acc = bp2[t];
        for (int k = 0; k < 64; ++k) acc = fmaf(p1[k], Wp2[k * 32 + t], acc);
        p2[t] = fmaxf(acc, 0.f);
    }
    __syncthreads();
    if (t == 0) {
        float acc = bp3[0];
        for (int k = 0; k < 32; ++k) acc = fmaf(p2[k], Wp3[k], acc);
        out[0] = 1.f / (1.f + expf(-acc));
    }
}

static inline char* align16(char* p) {
    return (char*)(((uintptr_t)p + 15) & ~(uintptr_t)15);
}

extern "C" void kernel_launch(void* const* d_in, const int* in_sizes, int n_in,
                              void* d_out, int out_size, void* d_ws, size_t ws_size,
                              hipStream_t stream) {
    const float* x   = (const float*)d_in[0];
    const int*   ei  = (const int*)d_in[1];
    const float* ea  = (const float*)d_in[2];
    const float* W1  = (const float*)d_in[3];
    const float* b1  = (const float*)d_in[4];
    const float* W2  = (const float*)d_in[5];
    const float* b2  = (const float*)d_in[6];
    const float* W3  = (const float*)d_in[7];
    const float* b3  = (const float*)d_in[8];
    const float* We1 = (const float*)d_in[9];
    const float* be1 = (const float*)d_in[10];
    const float* We2 = (const float*)d_in[11];
    const float* be2 = (const float*)d_in[12];
    const float* Wp1 = (const float*)d_in[13];
    const float* bp1 = (const float*)d_in[14];
    const float* Wp2 = (const float*)d_in[15];
    const float* bp2 = (const float*)d_in[16];
    const float* Wp3 = (const float*)d_in[17];
    const float* bp3 = (const float*)d_in[18];

    const int N = in_sizes[0] / 6;
    const int E = in_sizes[1] / 2;
    const int nbN = (N + 255) / 256;
    const int nbE = (E + 255) / 256;
    const size_t SB = (size_t)N * 64 * 2;  // one bf16 table = 12.8MB (>= E*4)

    // ---- workspace layout (~68 MB) ----
    char* p = (char*)d_ws;
    double* sums = (double*)p;          p = align16(p + 128 * sizeof(double));
    int* cntO = (int*)p;                p = align16(p + (size_t)N * 4);
    int* cntI = (int*)p;                p = align16(p + (size_t)N * 4);
    int* offO = (int*)p;                p = align16(p + ((size_t)N + 1) * 4);
    int* offI = (int*)p;                p = align16(p + ((size_t)N + 1) * 4);
    int* bsumA = (int*)p;               p = align16(p + 512 * 4);
    int* bsumB = (int*)p;               p = align16(p + 512 * 4);
    float* xp = (float*)p;              p = align16(p + (size_t)N * 6 * 4);
    float* dinv = (float*)p;            p = align16(p + (size_t)N * 4);
    uint2* in_pk = (uint2*)p;           p = align16(p + (size_t)E * 8);
    // U1: rankS/rankD die after k_place; reborn as bf16 ping-pong tables
    char* u1 = p;                       p = align16(p + 2 * SB);
    int* rankS = (int*)u1;
    int* rankD = (int*)(u1 + SB);
    unsigned short* sbufA = (unsigned short*)u1;
    unsigned short* sbufB = (unsigned short*)(u1 + SB);
    // U2: efp + out_eid die after k_nef_x
    char* u2 = p;
    unsigned* efp = (unsigned*)u2;
    unsigned* out_eid = (unsigned*)(u2 + (size_t)E * 12);

    const int TB = 256;
    dim3 blk(TB);

    k_zero<<<dim3(nbN), blk, 0, stream>>>(cntO, cntI, sums, N);
    k_front<<<dim3(nbE), blk, 0, stream>>>(ei, ea, We1, be1, We2, be2,
                                           efp, cntO, cntI, rankS, rankD, E);
    k_scan1<<<dim3(nbN), blk, 0, stream>>>(cntO, bsumA, N);
    k_scan1<<<dim3(nbN), blk, 0, stream>>>(cntI, bsumB, N);
    k_scan2<<<dim3(1), dim3(512), 0, stream>>>(bsumA, nbN, offO + N);
    k_scan2<<<dim3(1), dim3(512), 0, stream>>>(bsumB, nbN, offI + N);
    k_scan3off<<<dim3(nbN), blk, 0, stream>>>(cntO, bsumA, offO, N);
    k_scan3off<<<dim3(nbN), blk, 0, stream>>>(cntI, bsumB, offI, N);
    k_place<<<dim3(nbE), blk, 0, stream>>>(ei, rankS, rankD, offO, offI, out_eid, in_pk, E);
    k_nef_x<<<dim3(nbN), blk, 0, stream>>>(offO, out_eid, offI, in_pk, efp, x, xp, dinv, N);

    // layer 1 matmul (sbufA aliases rankS — dead after k_place)
    k_mm1<<<dim3(1024), blk, 0, stream>>>(xp, W1, dinv, sbufA, N);
    // layers 2,3 fused gather+mm; final fused gather+reduce
    k_gathermm<<<dim3(2048), blk, 0, stream>>>(offI, in_pk, dinv, sbufA, b1, W2, sbufB, N);
    k_gathermm<<<dim3(2048), blk, 0, stream>>>(offI, in_pk, dinv, sbufB, b2, W3, sbufA, N);
    k_gatherreduce<<<dim3(2048), blk, 0, stream>>>(offI, in_pk, dinv, sbufA, b3, sums, N);
    k_head<<<dim3(1), dim3(64), 0, stream>>>(sums, Wp1, bp1, Wp2, bp2, Wp3, bp3,
                                             (float*)d_out, N);
}